// Round 10
// baseline (435.156 us; speedup 1.0000x reference)
//
#include <hip/hip_runtime.h>
#include <hip/hip_bf16.h>
#include <math.h>
#include <stdint.h>

#define B_GRAPHS 64
#define N_NODES  2048
#define E_DIM    16
#define M_TOT    (B_GRAPHS * N_NODES)   // 131072
#define K_COND   64
#define MLP_IN   192
#define HID      512
#define POOLD    128
#define BN_EPS   1e-5f

typedef __attribute__((ext_vector_type(8))) short bfrag8;
typedef __attribute__((ext_vector_type(4))) float facc4;

__device__ __forceinline__ unsigned short f2b(float f) {
    unsigned int x = __builtin_bit_cast(unsigned int, f);
    unsigned int r = x + 0x7fffu + ((x >> 16) & 1u);
    return (unsigned short)(r >> 16);
}
__device__ __forceinline__ float b2f(unsigned short u) {
    unsigned int x = ((unsigned int)u) << 16;
    return __builtin_bit_cast(float, x);
}

// Branch-free GELU: erf via Abramowitz-Stegun 7.1.26 (|err| <= 1.5e-7).
__device__ __forceinline__ float gelu_fast(float y) {
    float x  = y * 0.70710678118654752440f;
    float ax = fabsf(x);
    float t  = __builtin_amdgcn_rcpf(fmaf(0.3275911f, ax, 1.0f));
    float p  = fmaf(1.061405429f, t, -1.453152027f);
    p = fmaf(p, t, 1.421413741f);
    p = fmaf(p, t, -0.284496736f);
    p = fmaf(p, t, 0.254829592f);
    p = p * t;
    float e = __expf(-x * x);
    float erfax = fmaf(-p, e, 1.0f);
    float erfx  = copysignf(erfax, x);
    return 0.5f * y * (1.0f + erfx);
}

#define GLOAD_LDS16(g, l)                                                        \
    __builtin_amdgcn_global_load_lds(                                            \
        (const __attribute__((address_space(1))) unsigned int*)(const void*)(g), \
        (__attribute__((address_space(3))) unsigned int*)(void*)(l), 16, 0, 0)

// ---------------- prep: pooled (LDS) -> gbias[g][n] = pooled . W1[n,64:192] + b1[n] ----------------
__global__ __launch_bounds__(512) void prep_kernel(const float* __restrict__ x,
                                                   const float* __restrict__ W1,
                                                   const float* __restrict__ b1,
                                                   float* __restrict__ gbias) {
    __shared__ float pl[POOLD];
    int g = blockIdx.x, t = threadIdx.x;
    if (t < 128) {
        int h = t >> 2, w = t & 3;
        const float* base = x + (size_t)g * N_NODES * E_DIM + (size_t)h * 64 * E_DIM + w * 4;
        float s = 0.f;
        #pragma unroll 4
        for (int r = 0; r < 64; ++r) {
            float4 v = *reinterpret_cast<const float4*>(base + (size_t)r * E_DIM);
            s += v.x + v.y + v.z + v.w;
        }
        pl[h * 4 + w] = s * (1.0f / 256.0f);
    }
    __syncthreads();
    const float* wr_ = W1 + (size_t)t * MLP_IN + K_COND;
    float s = b1[t];
    #pragma unroll 4
    for (int k = 0; k < POOLD; ++k) s = fmaf(pl[k], wr_[k], s);
    gbias[g * HID + t] = s;
}

__device__ __forceinline__ bfrag8 load_f32x8_as_bf16(const float* p) {
    float4 v0 = *reinterpret_cast<const float4*>(p);
    float4 v1 = *reinterpret_cast<const float4*>(p + 4);
    unsigned short t[8] = {f2b(v0.x), f2b(v0.y), f2b(v0.z), f2b(v0.w),
                           f2b(v1.x), f2b(v1.y), f2b(v1.z), f2b(v1.w)};
    return *reinterpret_cast<bfrag8*>(t);
}

// ------------- cvt: W2 fp32 -> W2s bf16, granule-swizzled per 32-short K-half -------------
// W2s[n][kt*64 + kh*32 + (g ^ ((n>>1)&3))*8 + j] = bf16(W2[n][kt*64 + kh*32 + g*8 + j])
__global__ __launch_bounds__(256) void cvt_kernel(const float* __restrict__ W2,
                                                  unsigned short* __restrict__ W2s) {
    int gid = blockIdx.x * 256 + threadIdx.x;   // 512*8 = 4096 chunks of 64 shorts
    int n = gid >> 3, ktt = gid & 7;
    const float* src = W2 + (size_t)n * HID + ktt * 64;
    unsigned short* dst = W2s + (size_t)n * HID + ktt * 64;
    int key = (n >> 1) & 3;
    #pragma unroll
    for (int h = 0; h < 2; ++h) {
        #pragma unroll
        for (int g = 0; g < 4; ++g) {
            const float* s8 = src + h * 32 + g * 8;
            unsigned short tmp[8] = {f2b(s8[0]), f2b(s8[1]), f2b(s8[2]), f2b(s8[3]),
                                     f2b(s8[4]), f2b(s8[5]), f2b(s8[6]), f2b(s8[7])};
            *reinterpret_cast<bfrag8*>(dst + h * 32 + (g ^ key) * 8) =
                *reinterpret_cast<bfrag8*>(tmp);
        }
    }
}

// ------------- GEMM1: H1 = cond[.,0:64] @ W1[.,0:64]^T + gbias[row>>11], fused stats -------------
// (round-9 version, verified) BM=128 x BN=512 full width, 8 waves, A staged once to LDS.
__global__ __launch_bounds__(512, 1) void gemm1_kernel(const float* __restrict__ A,
                                                       const float* __restrict__ W,
                                                       const float* __restrict__ gbias,
                                                       float* __restrict__ sums,
                                                       unsigned short* __restrict__ C) {
    __shared__ unsigned short As[128 * 64];      // 16KB, swizzled 16B granules
    __shared__ float sArr[HID], qArr[HID];
    const int t = threadIdx.x;
    const int r0 = blockIdx.x * 128;
    const int g = r0 >> 11;              // batch id (sorted repeat: row/2048)
    const int l = t & 63, w = t >> 6;
    const int wr = w >> 2, wc = w & 3;   // 2 x 4 waves
    const int ln = l & 15, kg = l >> 4;
    sArr[t] = 0.f; qArr[t] = 0.f;

    // stage cond block -> bf16 LDS (2 granules per thread)
    {
        const int cg = t & 7, rb = t >> 3;           // granule col, base row
        #pragma unroll
        for (int i = 0; i < 2; ++i) {
            int row = rb + i * 64;
            bfrag8 vv = load_f32x8_as_bf16(A + (size_t)(r0 + row) * K_COND + cg * 8);
            int dg = row * 8 + (cg ^ (row & 7));
            *reinterpret_cast<bfrag8*>(&As[dg * 8]) = vv;
        }
    }
    // B fragments for both K-steps (W1 fp32, inline cvt; L2-resident)
    bfrag8 bf0[8], bf1[8];
    #pragma unroll
    for (int b = 0; b < 8; ++b) {
        int RB = wc * 128 + b * 16 + ln;
        bf0[b] = load_f32x8_as_bf16(W + (size_t)RB * MLP_IN + kg * 8);
        bf1[b] = load_f32x8_as_bf16(W + (size_t)RB * MLP_IN + 32 + kg * 8);
    }
    __syncthreads();

    facc4 acc[4][8];
    const facc4 z = {0.f, 0.f, 0.f, 0.f};
    #pragma unroll
    for (int a = 0; a < 4; ++a)
        #pragma unroll
        for (int b = 0; b < 8; ++b) acc[a][b] = z;

    #pragma unroll
    for (int s = 0; s < 2; ++s) {
        bfrag8 af[4];
        #pragma unroll
        for (int a = 0; a < 4; ++a) {
            int RA = wr * 64 + a * 16 + ln;
            af[a] = *reinterpret_cast<const bfrag8*>(&As[(RA * 8 + ((s * 4 + kg) ^ (RA & 7))) * 8]);
        }
        #pragma unroll
        for (int a = 0; a < 4; ++a)
            #pragma unroll
            for (int b = 0; b < 8; ++b)
                acc[a][b] = __builtin_amdgcn_mfma_f32_16x16x32_bf16(
                    af[a], s == 0 ? bf0[b] : bf1[b], acc[a][b], 0, 0, 0);
    }

    const float* gb = gbias + (size_t)g * HID;
    float gbv[8];
    #pragma unroll
    for (int b = 0; b < 8; ++b) gbv[b] = gb[wc * 128 + b * 16 + ln];
    float cs[8], cq[8];
    #pragma unroll
    for (int b = 0; b < 8; ++b) { cs[b] = 0.f; cq[b] = 0.f; }
    #pragma unroll
    for (int a = 0; a < 4; ++a) {
        #pragma unroll
        for (int i = 0; i < 4; ++i) {
            size_t rbase = (size_t)(r0 + wr * 64 + a * 16 + kg * 4 + i) * HID + wc * 128 + ln;
            #pragma unroll
            for (int b = 0; b < 8; ++b) {
                float v = acc[a][b][i] + gbv[b];
                C[rbase + b * 16] = f2b(v);
                cs[b] += v; cq[b] = fmaf(v, v, cq[b]);
            }
        }
    }
    #pragma unroll
    for (int b = 0; b < 8; ++b) {
        cs[b] += __shfl_xor(cs[b], 16, 64); cq[b] += __shfl_xor(cq[b], 16, 64);
        cs[b] += __shfl_xor(cs[b], 32, 64); cq[b] += __shfl_xor(cq[b], 32, 64);
    }
    if (kg == 0) {
        #pragma unroll
        for (int b = 0; b < 8; ++b) {
            int cl = wc * 128 + b * 16 + ln;
            atomicAdd(&sArr[cl], cs[b]); atomicAdd(&qArr[cl], cq[b]);
        }
    }
    __syncthreads();
    atomicAdd(&sums[t], sArr[t]);
    atomicAdd(&sums[HID + t], qArr[t]);
}

// ------------- finalize: ss[0:512]=scale, ss[512:1024]=shift -------------
__global__ void finalize_kernel(const float* __restrict__ sums, const float* __restrict__ g,
                                const float* __restrict__ be, float* __restrict__ ss) {
    int n = threadIdx.x;  // 512
    float mean = sums[n] * (1.0f / M_TOT);
    float var = sums[HID + n] * (1.0f / M_TOT) - mean * mean;
    float sc = g[n] * rsqrtf(var + BN_EPS);
    ss[n] = sc;
    ss[HID + n] = be[n] - mean * sc;
}

// ------------- act: H1a[R][kt*64 + (g^(R&7))*8+j] = gelu(bn1(H1[R][kt*64+g*8+j])) -------------
// Writes the activated tensor pre-swizzled in gemm2's staging granule order.
__global__ __launch_bounds__(256) void act_kernel(const unsigned short* __restrict__ H1,
                                                  const float* __restrict__ ss,
                                                  unsigned short* __restrict__ H1a) {
    __shared__ float lss[2 * HID];
    int t = threadIdx.x;
    #pragma unroll
    for (int i = t; i < 2 * HID; i += 256) lss[i] = ss[i];
    __syncthreads();
    size_t gid = (size_t)blockIdx.x * 256 + t;   // 131072*8 chunks of 64 shorts
    int R = (int)(gid >> 3);
    int ktt = (int)(gid & 7);
    const unsigned short* src = H1 + (size_t)R * HID + ktt * 64;
    unsigned short* dst = H1a + (size_t)R * HID + ktt * 64;
    int key = R & 7;
    #pragma unroll
    for (int g = 0; g < 8; ++g) {
        bfrag8 v = *reinterpret_cast<const bfrag8*>(src + g * 8);
        unsigned short tmp[8];
        int cb = ktt * 64 + g * 8;
        #pragma unroll
        for (int j = 0; j < 8; ++j) {
            float xv = b2f((unsigned short)v[j]);
            tmp[j] = f2b(gelu_fast(fmaf(xv, lss[cb + j], lss[HID + cb + j])));
        }
        *reinterpret_cast<bfrag8*>(dst + (g ^ key) * 8) = *reinterpret_cast<bfrag8*>(tmp);
    }
}

// ------------- GEMM2: H2 = H1a @ W2s^T + b2, fused stats2 -------------
// 256x256 tile, BK=64, 8 waves (2Mx4N, wave tile 128x64), 4-phase counted-vmcnt
// pipeline (adapted m201): all staging via global_load_lds from pre-swizzled
// sources (linear copies), ds_read swizzle cancels -> conflict-free.
// A halves: row-folded {wr0,wr1} 16KB; B halves: K-split 16KB.
__global__ __launch_bounds__(512) void gemm2_kernel(const unsigned short* __restrict__ A,
                                                    const unsigned short* __restrict__ Bm,
                                                    const float* __restrict__ bias,
                                                    float* __restrict__ sums,
                                                    unsigned short* __restrict__ C) {
    __shared__ unsigned short As[2 * 2 * 8192];  // [buf][half][128 rows x 64] 64KB
    __shared__ unsigned short Bs[2 * 2 * 8192];  // [buf][kh][256 rows x 32]   64KB
    __shared__ float sArr[256], qArr[256];
    const int t = threadIdx.x;
    const int r0 = blockIdx.x * 256;
    const int c0 = blockIdx.y * 256;
    const int l = t & 63, w = t >> 6;            // 8 waves
    const int wr = w >> 2, wc = w & 3;           // 2 x 4; wave tile 128 x 64
    const int ln = l & 15, kg = l >> 4;
    if (t < 256) { sArr[t] = 0.f; qArr[t] = 0.f; }

    auto issueA = [&](int kt, int nbuf, int h) {
        #pragma unroll
        for (int q = 0; q < 2; ++q) {
            int R = r0 + q * 128 + h * 64 + w * 8 + (l >> 3);
            const unsigned short* src = A + (size_t)R * HID + kt * 64 + (l & 7) * 8;
            GLOAD_LDS16(src, &As[(nbuf * 2 + h) * 8192 + (q * 8 + w) * 512]);
        }
    };
    auto issueB = [&](int kt, int nbuf, int kh) {
        #pragma unroll
        for (int q = 0; q < 2; ++q) {
            int nb = (q * 8 + w) * 16 + (l >> 2);
            const unsigned short* src = Bm + (size_t)(c0 + nb) * HID + kt * 64 + kh * 32 + (l & 3) * 8;
            GLOAD_LDS16(src, &Bs[(nbuf * 2 + kh) * 8192 + (q * 8 + w) * 512]);
        }
    };

    bfrag8 af[4], bf[4];
    auto dsA = [&](int cbuf, int mh, int kh) {
        #pragma unroll
        for (int a = 0; a < 4; ++a) {
            int lr = wr * 64 + a * 16 + ln;
            int gcol = kh * 4 + kg;
            af[a] = *reinterpret_cast<const bfrag8*>(
                &As[(cbuf * 2 + mh) * 8192 + lr * 64 + ((gcol ^ (lr & 7)) * 8)]);
        }
    };
    auto dsB = [&](int cbuf, int kh) {
        #pragma unroll
        for (int b = 0; b < 4; ++b) {
            int RB = wc * 64 + b * 16 + ln;
            bf[b] = *reinterpret_cast<const bfrag8*>(
                &Bs[(cbuf * 2 + kh) * 8192 + RB * 32 + ((kg ^ ((RB >> 1) & 3)) * 8)]);
        }
    };

    facc4 acc[8][4];
    const facc4 z = {0.f, 0.f, 0.f, 0.f};
    #pragma unroll
    for (int ai = 0; ai < 8; ++ai)
        #pragma unroll
        for (int b = 0; b < 4; ++b) acc[ai][b] = z;

#define MFMA16(MH)                                                                  \
    do {                                                                            \
        __builtin_amdgcn_s_setprio(1);                                              \
        _Pragma("unroll") for (int a = 0; a < 4; ++a)                               \
            _Pragma("unroll") for (int b = 0; b < 4; ++b)                           \
                acc[(MH) * 4 + a][b] = __builtin_amdgcn_mfma_f32_16x16x32_bf16(     \
                    af[a], bf[b], acc[(MH) * 4 + a][b], 0, 0, 0);                   \
        __builtin_amdgcn_s_setprio(0);                                              \
    } while (0)

    // prologue: stage K-tile 0 -> buf0 (order: Ah0, Ah1, Bk0, Bk1), full drain
    issueA(0, 0, 0); issueA(0, 0, 1); issueB(0, 0, 0); issueB(0, 0, 1);
    asm volatile("s_waitcnt vmcnt(0)" ::: "memory");
    __syncthreads();

    for (int tt = 0; tt < 8; ++tt) {
        const int c = tt & 1, n = c ^ 1;
        const bool st = (tt < 7);
        // P0 (mh0, kh0)
        dsA(c, 0, 0); dsB(c, 0);
        if (st) issueA(tt + 1, n, 0);
        __builtin_amdgcn_s_barrier();
        MFMA16(0);
        __builtin_amdgcn_s_barrier();
        // P1 (mh1, kh0) — reuse bf
        dsA(c, 1, 0);
        if (st) issueA(tt + 1, n, 1);
        __builtin_amdgcn_s_barrier();
        MFMA16(1);
        if (st) asm volatile("s_waitcnt vmcnt(4)" ::: "memory");   // retire prev B-kh1
        else    asm volatile("s_waitcnt vmcnt(0)" ::: "memory");
        __builtin_amdgcn_s_barrier();
        // P2 (mh0, kh1)
        dsA(c, 0, 1); dsB(c, 1);
        if (st) issueB(tt + 1, n, 0);
        __builtin_amdgcn_s_barrier();
        MFMA16(0);
        __builtin_amdgcn_s_barrier();
        // P3 (mh1, kh1)
        dsA(c, 1, 1);
        if (st) issueB(tt + 1, n, 1);
        __builtin_amdgcn_s_barrier();
        MFMA16(1);
        if (st) asm volatile("s_waitcnt vmcnt(2)" ::: "memory");   // retire A(t+1)+B-kh0(t+1)
        __builtin_amdgcn_s_barrier();
    }
#undef MFMA16

    float bb[4];
    #pragma unroll
    for (int b = 0; b < 4; ++b) bb[b] = bias[c0 + wc * 64 + b * 16 + ln];
    float cs[4] = {0.f, 0.f, 0.f, 0.f}, cq[4] = {0.f, 0.f, 0.f, 0.f};
    #pragma unroll
    for (int ai = 0; ai < 8; ++ai) {
        #pragma unroll
        for (int i = 0; i < 4; ++i) {
            int row = r0 + wr * 128 + (ai >> 2) * 64 + (ai & 3) * 16 + kg * 4 + i;
            size_t rbase = (size_t)row * HID + c0 + wc * 64 + ln;
            #pragma unroll
            for (int b = 0; b < 4; ++b) {
                float v = acc[ai][b][i] + bb[b];
                C[rbase + b * 16] = f2b(v);
                cs[b] += v; cq[b] = fmaf(v, v, cq[b]);
            }
        }
    }
    #pragma unroll
    for (int b = 0; b < 4; ++b) {
        cs[b] += __shfl_xor(cs[b], 16, 64); cq[b] += __shfl_xor(cq[b], 16, 64);
        cs[b] += __shfl_xor(cs[b], 32, 64); cq[b] += __shfl_xor(cq[b], 32, 64);
    }
    __syncthreads();
    if (kg == 0) {
        #pragma unroll
        for (int b = 0; b < 4; ++b) {
            int cl = wc * 64 + b * 16 + ln;
            atomicAdd(&sArr[cl], cs[b]); atomicAdd(&qArr[cl], cq[b]);
        }
    }
    __syncthreads();
    if (t < 256) {
        atomicAdd(&sums[c0 + t], sArr[t]);
        atomicAdd(&sums[HID + c0 + t], qArr[t]);
    }
}

// ------------- G3: out[m][0:3] = gelu(bn2(H2[m])) . W3^T + b3  (8 lanes per row) -------------
__global__ __launch_bounds__(256) void g3_kernel(const unsigned short* __restrict__ H2,
                                                 const float* __restrict__ ss2,
                                                 const float* __restrict__ W3,
                                                 const float* __restrict__ b3,
                                                 float* __restrict__ out) {
    __shared__ float lss[2 * HID];
    __shared__ float lw3[3 * HID];
    int t = threadIdx.x;
    for (int i = t; i < 2 * HID; i += 256) lss[i] = ss2[i];
    for (int i = t; i < 3 * HID; i += 256) lw3[i] = W3[i];
    __syncthreads();
    int l = t & 63, w = t >> 6;
    int rsub = l >> 3, lk = l & 7;
    int row = blockIdx.x * 32 + w * 8 + rsub;
    const unsigned short* p = H2 + (size_t)row * HID;
    float o0 = 0.f, o1 = 0.f, o2 = 0.f;
    #pragma unroll
    for (int it = 0; it < 8; ++it) {
        int k = it * 64 + lk * 8;
        bfrag8 v = *reinterpret_cast<const bfrag8*>(p + k);
        #pragma unroll
        for (int j = 0; j < 8; ++j) {
            float x = b2f((unsigned short)v[j]);
            float y = fmaf(x, lss[k + j], lss[HID + k + j]);
            y = gelu_fast(y);
            o0 = fmaf(y, lw3[k + j], o0);
            o1 = fmaf(y, lw3[HID + k + j], o1);
            o2 = fmaf(y, lw3[2 * HID + k + j], o2);
        }
    }
    #pragma unroll
    for (int m = 1; m < 8; m <<= 1) {
        o0 += __shfl_xor(o0, m, 64);
        o1 += __shfl_xor(o1, m, 64);
        o2 += __shfl_xor(o2, m, 64);
    }
    if (lk == 0) {
        out[(size_t)row * 3 + 0] = o0 + b3[0];
        out[(size_t)row * 3 + 1] = o1 + b3[1];
        out[(size_t)row * 3 + 2] = o2 + b3[2];
    }
}

extern "C" void kernel_launch(void* const* d_in, const int* in_sizes, int n_in,
                              void* d_out, int out_size, void* d_ws, size_t ws_size,
                              hipStream_t stream) {
    const float* x     = (const float*)d_in[0];
    const float* cond  = (const float*)d_in[2];
    const float* W1    = (const float*)d_in[3];
    const float* b1    = (const float*)d_in[4];
    const float* g1    = (const float*)d_in[5];
    const float* be1   = (const float*)d_in[6];
    const float* W2    = (const float*)d_in[7];
    const float* b2    = (const float*)d_in[8];
    const float* g2    = (const float*)d_in[9];
    const float* be2   = (const float*)d_in[10];
    const float* W3    = (const float*)d_in[11];
    const float* b3    = (const float*)d_in[12];

    const size_t H_BYTES = (size_t)M_TOT * HID * 2;  // 134,217,728
    if (ws_size < 2 * H_BYTES) return;               // clean fail instead of OOB crash
    char* ws = (char*)d_ws;
    unsigned short* H1   = (unsigned short*)ws;               // gemm1 out; dead after act
    unsigned short* H1a  = (unsigned short*)(ws + H_BYTES);   // act out (swizzled); dead after gemm2
    unsigned short* H2o  = (unsigned short*)ws;               // gemm2 out (reuses H1 region)
    float*          ss2  = (float*)(ws + H_BYTES);            // finalize2 out (reuses H1a region)

    // Small scratch lives in d_out (1.57MB) until g3 overwrites all of it.
    float* outf   = (float*)d_out;
    float* gbias  = outf;                        // 32768 floats
    float* sums1  = gbias + B_GRAPHS * HID;      // 1024 (sum | sumsq)
    float* sums2  = sums1 + 2 * HID;             // 1024
    float* ss1    = sums2 + 2 * HID;             // 1024
    unsigned short* W2s = (unsigned short*)(ss1 + 2 * HID);   // 262144 shorts (512KB)

    hipMemsetAsync(sums1, 0, 2 * 2 * HID * sizeof(float), stream);

    prep_kernel<<<B_GRAPHS, 512, 0, stream>>>(x, W1, b1, gbias);
    cvt_kernel<<<(HID * 8) / 256, 256, 0, stream>>>(W2, W2s);

    gemm1_kernel<<<dim3(M_TOT / 128, 1), 512, 0, stream>>>(
        cond, W1, gbias, sums1, H1);
    finalize_kernel<<<1, HID, 0, stream>>>(sums1, g1, be1, ss1);
    act_kernel<<<(M_TOT * 8) / 256, 256, 0, stream>>>(H1, ss1, H1a);

    gemm2_kernel<<<dim3(M_TOT / 256, HID / 256), 512, 0, stream>>>(
        H1a, W2s, b2, sums2, H2o);
    finalize_kernel<<<1, HID, 0, stream>>>(sums2, g2, be2, ss2);

    g3_kernel<<<M_TOT / 32, 256, 0, stream>>>(H2o, ss2, W3, b3, outf);
}

// Round 11
// 349.043 us; speedup vs baseline: 1.2467x; 1.2467x over previous
//
#include <hip/hip_runtime.h>
#include <hip/hip_bf16.h>
#include <math.h>
#include <stdint.h>

#define B_GRAPHS 64
#define N_NODES  2048
#define E_DIM    16
#define M_TOT    (B_GRAPHS * N_NODES)   // 131072
#define K_COND   64
#define MLP_IN   192
#define HID      512
#define POOLD    128
#define BN_EPS   1e-5f

typedef __attribute__((ext_vector_type(8))) short bfrag8;
typedef __attribute__((ext_vector_type(4))) short bfrag4;
typedef __attribute__((ext_vector_type(4))) float facc4;

__device__ __forceinline__ unsigned short f2b(float f) {
    unsigned int x = __builtin_bit_cast(unsigned int, f);
    unsigned int r = x + 0x7fffu + ((x >> 16) & 1u);
    return (unsigned short)(r >> 16);
}
__device__ __forceinline__ float b2f(unsigned short u) {
    unsigned int x = ((unsigned int)u) << 16;
    return __builtin_bit_cast(float, x);
}

// Branch-free GELU: erf via Abramowitz-Stegun 7.1.26 (|err| <= 1.5e-7).
__device__ __forceinline__ float gelu_fast(float y) {
    float x  = y * 0.70710678118654752440f;
    float ax = fabsf(x);
    float t  = __builtin_amdgcn_rcpf(fmaf(0.3275911f, ax, 1.0f));
    float p  = fmaf(1.061405429f, t, -1.453152027f);
    p = fmaf(p, t, 1.421413741f);
    p = fmaf(p, t, -0.284496736f);
    p = fmaf(p, t, 0.254829592f);
    p = p * t;
    float e = __expf(-x * x);
    float erfax = fmaf(-p, e, 1.0f);
    float erfx  = copysignf(erfax, x);
    return 0.5f * y * (1.0f + erfx);
}

// ---------------- prep: pooled (LDS) -> gbias[g][n] = pooled . W1[n,64:192] + b1[n] ----------------
__global__ __launch_bounds__(512) void prep_kernel(const float* __restrict__ x,
                                                   const float* __restrict__ W1,
                                                   const float* __restrict__ b1,
                                                   float* __restrict__ gbias) {
    __shared__ float pl[POOLD];
    int g = blockIdx.x, t = threadIdx.x;
    if (t < 128) {
        int h = t >> 2, w = t & 3;
        const float* base = x + (size_t)g * N_NODES * E_DIM + (size_t)h * 64 * E_DIM + w * 4;
        float s = 0.f;
        #pragma unroll 4
        for (int r = 0; r < 64; ++r) {
            float4 v = *reinterpret_cast<const float4*>(base + (size_t)r * E_DIM);
            s += v.x + v.y + v.z + v.w;
        }
        pl[h * 4 + w] = s * (1.0f / 256.0f);
    }
    __syncthreads();
    const float* wr_ = W1 + (size_t)t * MLP_IN + K_COND;
    float s = b1[t];
    #pragma unroll 4
    for (int k = 0; k < POOLD; ++k) s = fmaf(pl[k], wr_[k], s);
    gbias[g * HID + t] = s;
}

// ------------- contiguous fp32 -> bf16 (for W2) -------------
__global__ __launch_bounds__(256) void cvt_kernel(const float* __restrict__ s,
                                                  unsigned short* __restrict__ d) {
    size_t i = ((size_t)blockIdx.x * 256 + threadIdx.x) * 8;
    float4 v0 = *reinterpret_cast<const float4*>(s + i);
    float4 v1 = *reinterpret_cast<const float4*>(s + i + 4);
    unsigned short t[8] = {f2b(v0.x), f2b(v0.y), f2b(v0.z), f2b(v0.w),
                           f2b(v1.x), f2b(v1.y), f2b(v1.z), f2b(v1.w)};
    *reinterpret_cast<bfrag8*>(d + i) = *reinterpret_cast<bfrag8*>(t);
}

__device__ __forceinline__ bfrag8 load_f32x8_as_bf16(const float* p) {
    float4 v0 = *reinterpret_cast<const float4*>(p);
    float4 v1 = *reinterpret_cast<const float4*>(p + 4);
    unsigned short t[8] = {f2b(v0.x), f2b(v0.y), f2b(v0.z), f2b(v0.w),
                           f2b(v1.x), f2b(v1.y), f2b(v1.z), f2b(v1.w)};
    return *reinterpret_cast<bfrag8*>(t);
}

// ------------- stats1: column sum/sumsq of H1 = cond @ W1a^T + gbias (NO H1 store) -------------
// r9 gemm1 structure (verified) minus the C-write.
__global__ __launch_bounds__(512, 1) void stats1_kernel(const float* __restrict__ A,
                                                        const float* __restrict__ W,
                                                        const float* __restrict__ gbias,
                                                        float* __restrict__ sums) {
    __shared__ unsigned short As[128 * 64];      // 16KB, swizzled 16B granules
    __shared__ float sArr[HID], qArr[HID];
    const int t = threadIdx.x;
    const int r0 = blockIdx.x * 128;
    const int g = r0 >> 11;              // batch id (sorted repeat: row/2048)
    const int l = t & 63, w = t >> 6;
    const int wr = w >> 2, wc = w & 3;   // 2 x 4 waves
    const int ln = l & 15, kg = l >> 4;
    sArr[t] = 0.f; qArr[t] = 0.f;

    {
        const int cg = t & 7, rb = t >> 3;
        #pragma unroll
        for (int i = 0; i < 2; ++i) {
            int row = rb + i * 64;
            bfrag8 vv = load_f32x8_as_bf16(A + (size_t)(r0 + row) * K_COND + cg * 8);
            int dg = row * 8 + (cg ^ (row & 7));
            *reinterpret_cast<bfrag8*>(&As[dg * 8]) = vv;
        }
    }
    bfrag8 bf0[8], bf1[8];
    #pragma unroll
    for (int b = 0; b < 8; ++b) {
        int RB = wc * 128 + b * 16 + ln;
        bf0[b] = load_f32x8_as_bf16(W + (size_t)RB * MLP_IN + kg * 8);
        bf1[b] = load_f32x8_as_bf16(W + (size_t)RB * MLP_IN + 32 + kg * 8);
    }
    __syncthreads();

    facc4 acc[4][8];
    const facc4 z = {0.f, 0.f, 0.f, 0.f};
    #pragma unroll
    for (int a = 0; a < 4; ++a)
        #pragma unroll
        for (int b = 0; b < 8; ++b) acc[a][b] = z;

    #pragma unroll
    for (int s = 0; s < 2; ++s) {
        bfrag8 af[4];
        #pragma unroll
        for (int a = 0; a < 4; ++a) {
            int RA = wr * 64 + a * 16 + ln;
            af[a] = *reinterpret_cast<const bfrag8*>(&As[(RA * 8 + ((s * 4 + kg) ^ (RA & 7))) * 8]);
        }
        #pragma unroll
        for (int a = 0; a < 4; ++a)
            #pragma unroll
            for (int b = 0; b < 8; ++b)
                acc[a][b] = __builtin_amdgcn_mfma_f32_16x16x32_bf16(
                    af[a], s == 0 ? bf0[b] : bf1[b], acc[a][b], 0, 0, 0);
    }

    const float* gb = gbias + (size_t)g * HID;
    float gbv[8];
    #pragma unroll
    for (int b = 0; b < 8; ++b) gbv[b] = gb[wc * 128 + b * 16 + ln];
    float cs[8], cq[8];
    #pragma unroll
    for (int b = 0; b < 8; ++b) { cs[b] = 0.f; cq[b] = 0.f; }
    #pragma unroll
    for (int a = 0; a < 4; ++a) {
        #pragma unroll
        for (int i = 0; i < 4; ++i) {
            #pragma unroll
            for (int b = 0; b < 8; ++b) {
                float v = acc[a][b][i] + gbv[b];
                cs[b] += v; cq[b] = fmaf(v, v, cq[b]);
            }
        }
    }
    #pragma unroll
    for (int b = 0; b < 8; ++b) {
        cs[b] += __shfl_xor(cs[b], 16, 64); cq[b] += __shfl_xor(cq[b], 16, 64);
        cs[b] += __shfl_xor(cs[b], 32, 64); cq[b] += __shfl_xor(cq[b], 32, 64);
    }
    if (kg == 0) {
        #pragma unroll
        for (int b = 0; b < 8; ++b) {
            int cl = wc * 128 + b * 16 + ln;
            atomicAdd(&sArr[cl], cs[b]); atomicAdd(&qArr[cl], cq[b]);
        }
    }
    __syncthreads();
    atomicAdd(&sums[t], sArr[t]);
    atomicAdd(&sums[HID + t], qArr[t]);
}

// ------------- finalize: ss[0:512]=scale, ss[512:1024]=shift -------------
__global__ void finalize_kernel(const float* __restrict__ sums, const float* __restrict__ g,
                                const float* __restrict__ be, float* __restrict__ ss) {
    int n = threadIdx.x;  // 512
    float mean = sums[n] * (1.0f / M_TOT);
    float var = sums[HID + n] * (1.0f / M_TOT) - mean * mean;
    float sc = g[n] * rsqrtf(var + BN_EPS);
    ss[n] = sc;
    ss[HID + n] = be[n] - mean * sc;
}

// ------------- fused2: H2 = gelu(bn1(cond@W1a^T + gbias)) @ W2^T + b2, fused stats2 -------------
// Phase 1: recompute H1-tile via TRANSPOSED mfma (A=W1-rows, B=cond-rows) so each
//   lane holds 4 consecutive H1-columns of one row -> bn+gelu -> one ds_write_b64
//   into K-resident As[128][512] (8B-granule XOR-swizzle, key row&15).
// Phase 2: barrier-free 16-step K-loop; A-frags from LDS (2x b64), B-frags (W2 bf16,
//   L2-resident) global->reg with 2-deep prefetch. No H1 HBM traffic at all.
__global__ __launch_bounds__(512, 1) void fused2_kernel(const float* __restrict__ cond,
                                                        const float* __restrict__ W1,
                                                        const float* __restrict__ gbias,
                                                        const float* __restrict__ sums1,
                                                        const float* __restrict__ g1,
                                                        const float* __restrict__ be1,
                                                        const unsigned short* __restrict__ W2bf,
                                                        const float* __restrict__ bias,
                                                        float* __restrict__ sums,
                                                        unsigned short* __restrict__ H2) {
    __shared__ unsigned short As[128 * 512];     // 128KB
    __shared__ float lss[2 * HID];               // 4KB
    __shared__ float sArr[HID], qArr[HID];       // 4KB  (total 136KB)
    const int t = threadIdx.x;
    const int r0 = blockIdx.x * 128;
    const int g = r0 >> 11;
    const int l = t & 63, w = t >> 6;            // 8 waves
    const int wr = w >> 2, wc = w & 3;           // 2 x 4
    const int ln = l & 15, kg = l >> 4;

    // BN1 scale/shift from raw sums
    {
        const float inv = 1.0f / (float)M_TOT;
        float mean = sums1[t] * inv;
        float var  = sums1[HID + t] * inv - mean * mean;
        float sc   = g1[t] * rsqrtf(var + BN_EPS);
        lss[t] = sc;
        lss[HID + t] = be1[t] - mean * sc;
    }
    sArr[t] = 0.f; qArr[t] = 0.f;
    __syncthreads();   // lss ready

    // ---- Phase 1: transposed recompute of H1 tile ----
    {
        facc4 accT[8][4];
        const facc4 z = {0.f, 0.f, 0.f, 0.f};
        #pragma unroll
        for (int b = 0; b < 8; ++b)
            #pragma unroll
            for (int a = 0; a < 4; ++a) accT[b][a] = z;

        #pragma unroll
        for (int ks = 0; ks < 2; ++ks) {
            bfrag8 afw[8], bfc[4];
            #pragma unroll
            for (int b = 0; b < 8; ++b)
                afw[b] = load_f32x8_as_bf16(
                    W1 + (size_t)(wc * 128 + b * 16 + ln) * MLP_IN + ks * 32 + kg * 8);
            #pragma unroll
            for (int a = 0; a < 4; ++a)
                bfc[a] = load_f32x8_as_bf16(
                    cond + (size_t)(r0 + wr * 64 + a * 16 + ln) * K_COND + ks * 32 + kg * 8);
            #pragma unroll
            for (int b = 0; b < 8; ++b)
                #pragma unroll
                for (int a = 0; a < 4; ++a)
                    accT[b][a] = __builtin_amdgcn_mfma_f32_16x16x32_bf16(
                        afw[b], bfc[a], accT[b][a], 0, 0, 0);
        }
        // bn + gelu + scatter: lane holds H1[m][n0..n0+3], m = wr*64+a*16+ln, n0 = wc*128+b*16+kg*4
        #pragma unroll
        for (int b = 0; b < 8; ++b) {
            const int n0 = wc * 128 + b * 16 + kg * 4;
            facc4 sc4 = *reinterpret_cast<const facc4*>(&lss[n0]);
            facc4 sh4 = *reinterpret_cast<const facc4*>(&lss[HID + n0]);
            facc4 gb4 = *reinterpret_cast<const facc4*>(&gbias[(size_t)g * HID + n0]);
            #pragma unroll
            for (int a = 0; a < 4; ++a) {
                const int m = wr * 64 + a * 16 + ln;
                bfrag4 o;
                #pragma unroll
                for (int i = 0; i < 4; ++i) {
                    float h = accT[b][a][i] + gb4[i];
                    o[i] = (short)f2b(gelu_fast(fmaf(h, sc4[i], sh4[i])));
                }
                const int G = (wc * 32 + b * 4 + kg) ^ (m & 15);
                *reinterpret_cast<bfrag4*>(&As[m * 512 + G * 4]) = o;
            }
        }
    }
    __syncthreads();   // As fully written

    // ---- Phase 2: barrier-free K-loop ----
    facc4 acc[4][8];
    {
        const facc4 z = {0.f, 0.f, 0.f, 0.f};
        #pragma unroll
        for (int a = 0; a < 4; ++a)
            #pragma unroll
            for (int b = 0; b < 8; ++b) acc[a][b] = z;
    }
    bfrag8 bfv[3][8];
#define LOADB(KT, SLOT)                                                          \
    _Pragma("unroll") for (int b = 0; b < 8; ++b)                                \
        bfv[SLOT][b] = *reinterpret_cast<const bfrag8*>(                         \
            &W2bf[(size_t)(wc * 128 + b * 16 + ln) * HID + (KT) * 32 + kg * 8]);
    LOADB(0, 0);
    LOADB(1, 1);
    union U8 { bfrag8 v; bfrag4 h[2]; };
    #pragma unroll
    for (int kt = 0; kt < 16; ++kt) {
        const int cs_ = kt % 3, ns_ = (kt + 2) % 3;
        if (kt < 14) { LOADB(kt + 2, ns_); }
        bfrag8 af[4];
        #pragma unroll
        for (int a = 0; a < 4; ++a) {
            const int r = wr * 64 + a * 16 + ln;
            const int g0 = (8 * kt + 2 * kg) ^ (r & 15);
            const int g1i = (8 * kt + 2 * kg + 1) ^ (r & 15);
            U8 u;
            u.h[0] = *reinterpret_cast<const bfrag4*>(&As[r * 512 + g0 * 4]);
            u.h[1] = *reinterpret_cast<const bfrag4*>(&As[r * 512 + g1i * 4]);
            af[a] = u.v;
        }
        #pragma unroll
        for (int a = 0; a < 4; ++a)
            #pragma unroll
            for (int b = 0; b < 8; ++b)
                acc[a][b] = __builtin_amdgcn_mfma_f32_16x16x32_bf16(
                    af[a], bfv[cs_][b], acc[a][b], 0, 0, 0);
    }
#undef LOADB

    // ---- epilogue: bias, H2 store, stats2 ----
    float bb[8];
    #pragma unroll
    for (int b = 0; b < 8; ++b) bb[b] = bias[wc * 128 + b * 16 + ln];
    float cs[8], cq[8];
    #pragma unroll
    for (int b = 0; b < 8; ++b) { cs[b] = 0.f; cq[b] = 0.f; }
    #pragma unroll
    for (int a = 0; a < 4; ++a) {
        #pragma unroll
        for (int i = 0; i < 4; ++i) {
            size_t rbase = (size_t)(r0 + wr * 64 + a * 16 + kg * 4 + i) * HID + wc * 128 + ln;
            #pragma unroll
            for (int b = 0; b < 8; ++b) {
                float v = acc[a][b][i] + bb[b];
                H2[rbase + b * 16] = f2b(v);
                cs[b] += v; cq[b] = fmaf(v, v, cq[b]);
            }
        }
    }
    #pragma unroll
    for (int b = 0; b < 8; ++b) {
        cs[b] += __shfl_xor(cs[b], 16, 64); cq[b] += __shfl_xor(cq[b], 16, 64);
        cs[b] += __shfl_xor(cs[b], 32, 64); cq[b] += __shfl_xor(cq[b], 32, 64);
    }
    if (kg == 0) {
        #pragma unroll
        for (int b = 0; b < 8; ++b) {
            int cl = wc * 128 + b * 16 + ln;
            atomicAdd(&sArr[cl], cs[b]); atomicAdd(&qArr[cl], cq[b]);
        }
    }
    __syncthreads();
    atomicAdd(&sums[t], sArr[t]);
    atomicAdd(&sums[HID + t], qArr[t]);
}

// ------------- G3: out[m][0:3] = gelu(bn2(H2[m])) . W3^T + b3  (8 lanes per row) -------------
__global__ __launch_bounds__(256) void g3_kernel(const unsigned short* __restrict__ H2,
                                                 const float* __restrict__ ss2,
                                                 const float* __restrict__ W3,
                                                 const float* __restrict__ b3,
                                                 float* __restrict__ out) {
    __shared__ float lss[2 * HID];
    __shared__ float lw3[3 * HID];
    int t = threadIdx.x;
    for (int i = t; i < 2 * HID; i += 256) lss[i] = ss2[i];
    for (int i = t; i < 3 * HID; i += 256) lw3[i] = W3[i];
    __syncthreads();
    int l = t & 63, w = t >> 6;
    int rsub = l >> 3, lk = l & 7;
    int row = blockIdx.x * 32 + w * 8 + rsub;
    const unsigned short* p = H2 + (size_t)row * HID;
    float o0 = 0.f, o1 = 0.f, o2 = 0.f;
    #pragma unroll
    for (int it = 0; it < 8; ++it) {
        int k = it * 64 + lk * 8;
        bfrag8 v = *reinterpret_cast<const bfrag8*>(p + k);
        #pragma unroll
        for (int j = 0; j < 8; ++j) {
            float x = b2f((unsigned short)v[j]);
            float y = fmaf(x, lss[k + j], lss[HID + k + j]);
            y = gelu_fast(y);
            o0 = fmaf(y, lw3[k + j], o0);
            o1 = fmaf(y, lw3[HID + k + j], o1);
            o2 = fmaf(y, lw3[2 * HID + k + j], o2);
        }
    }
    #pragma unroll
    for (int m = 1; m < 8; m <<= 1) {
        o0 += __shfl_xor(o0, m, 64);
        o1 += __shfl_xor(o1, m, 64);
        o2 += __shfl_xor(o2, m, 64);
    }
    if (lk == 0) {
        out[(size_t)row * 3 + 0] = o0 + b3[0];
        out[(size_t)row * 3 + 1] = o1 + b3[1];
        out[(size_t)row * 3 + 2] = o2 + b3[2];
    }
}

extern "C" void kernel_launch(void* const* d_in, const int* in_sizes, int n_in,
                              void* d_out, int out_size, void* d_ws, size_t ws_size,
                              hipStream_t stream) {
    const float* x     = (const float*)d_in[0];
    const float* cond  = (const float*)d_in[2];
    const float* W1    = (const float*)d_in[3];
    const float* b1    = (const float*)d_in[4];
    const float* g1    = (const float*)d_in[5];
    const float* be1   = (const float*)d_in[6];
    const float* W2    = (const float*)d_in[7];
    const float* b2    = (const float*)d_in[8];
    const float* g2    = (const float*)d_in[9];
    const float* be2   = (const float*)d_in[10];
    const float* W3    = (const float*)d_in[11];
    const float* b3    = (const float*)d_in[12];

    const size_t H_BYTES = (size_t)M_TOT * HID * 2;  // 134,217,728
    if (ws_size < H_BYTES + 8192) return;            // clean fail instead of OOB crash
    char* ws = (char*)d_ws;
    unsigned short* H2  = (unsigned short*)ws;       // only big intermediate left
    float*          ss2 = (float*)(ws + H_BYTES);    // 4KB past H2

    // Small scratch lives in d_out (1.57MB) until g3 overwrites all of it.
    float* outf   = (float*)d_out;
    float* gbias  = outf;                        // 32768 floats
    float* sums1  = gbias + B_GRAPHS * HID;      // 1024 (sum | sumsq)
    float* sums2  = sums1 + 2 * HID;             // 1024
    unsigned short* W2bf = (unsigned short*)(sums2 + 2 * HID);  // 262144 shorts (512KB)

    hipMemsetAsync(sums1, 0, 2 * 2 * HID * sizeof(float), stream);

    prep_kernel<<<B_GRAPHS, 512, 0, stream>>>(x, W1, b1, gbias);
    cvt_kernel<<<(HID * HID / 8) / 256, 256, 0, stream>>>(W2, W2bf);

    stats1_kernel<<<dim3(M_TOT / 128, 1), 512, 0, stream>>>(cond, W1, gbias, sums1);

    fused2_kernel<<<dim3(M_TOT / 128, 1), 512, 0, stream>>>(
        cond, W1, gbias, sums1, g1, be1, W2bf, b2, sums2, H2);

    finalize_kernel<<<1, HID, 0, stream>>>(sums2, g2, be2, ss2);

    g3_kernel<<<M_TOT / 32, 256, 0, stream>>>(H2, ss2, W3, b3, outf);
}